// Round 3
// baseline (10363.255 us; speedup 1.0000x reference)
//
#include <hip/hip_runtime.h>

// RnnTagger (f32 inputs, f32 outputs — per template dtype rule):
//   tokens[64*512] i32; emb[50000,256] f32; W_ih[1536,256] f32; W_hh[1536,512] f32;
//   b_ih[1536] f32; b_hh[1536] f32; W_tag[64,512] f32; b_tag[64] f32.
//   d_out (f32): tag_logits [64,512,64] then preds [64,512] flat.
//
// f32-faithful MFMA: every f32 operand x is split x ~= hi + lo/4096 with
// hi,lo f16 (11-bit mantissa => x captured to ~2^-22). Product via 3 f16
// MFMAs: acc_m += Ah*Bh; acc_s += Ah*Bl + Al*Bh; result = acc_m + acc_s/4096.
// Per-product error ~2^-22 * |a||b| — argmax-safe vs np f32 ref (min top-2
// logit gap over 32768 rows ~ 5e-6 >> accumulated error ~3e-7).
//
// ws (72,220,928 B):
//   [0,256)              4 cluster barrier counters
//   [256,+262144)        h dbuf  [buf2][tri2][64][512] f16
//   [262400,+3145728)    whh2    [tri2][1536][512] f16
//   [3408128,+1572864)   wih2    [tri2][1536][256] f16
//   [4980992,+131072)    wtag2   [tri2][64][512] f16
//   [5112064,+67108864)  st      [b*512+t][512] f32

typedef unsigned short ushortT;
typedef float f32x4 __attribute__((ext_vector_type(4)));
typedef _Float16 f16x8 __attribute__((ext_vector_type(8)));

#define MFMAH(a, b, c) __builtin_amdgcn_mfma_f32_16x16x32_f16((a), (b), (c), 0, 0, 0)
#define KSC (1.0f / 4096.0f)

__device__ __forceinline__ void splitf(float x, ushortT& hi, ushortT& lo) {
    _Float16 h = (_Float16)x;
    float r = x - (float)h;
    _Float16 l = (_Float16)(r * 4096.0f);
    hi = __builtin_bit_cast(ushortT, h);
    lo = __builtin_bit_cast(ushortT, l);
}

#define HB_BUF 65536   // f16 elems per h buffer (2 tri * 64 * 512)
#define HB_TRI 32768

// ---------- k0: split W_hh / W_ih / W_tag into f16 hi/lo pairs ----------
__global__ __launch_bounds__(256) void split_weights(
    const float* __restrict__ Whh, const float* __restrict__ Wih,
    const float* __restrict__ Wtag, ushortT* __restrict__ wh2,
    ushortT* __restrict__ wi2, ushortT* __restrict__ wt2)
{
    const int i = blockIdx.x * 256 + threadIdx.x;
    ushortT hi, lo;
    if (i < 786432) {                       // 1536*512
        splitf(Whh[i], hi, lo);
        wh2[i] = hi; wh2[786432 + i] = lo;
    } else if (i < 786432 + 393216) {       // 1536*256
        const int j = i - 786432;
        splitf(Wih[j], hi, lo);
        wi2[j] = hi; wi2[393216 + j] = lo;
    } else if (i < 786432 + 393216 + 32768) {   // 64*512
        const int j = i - 786432 - 393216;
        splitf(Wtag[j], hi, lo);
        wt2[j] = hi; wt2[32768 + j] = lo;
    }
}

// ---------- k1: zero counters + h double buffer ----------
__global__ void init_ws(uint4* p) {
    int i = blockIdx.x * blockDim.x + threadIdx.x;
    if (i < 16400) {   // 262400 B / 16
        uint4 z; z.x = 0u; z.y = 0u; z.z = 0u; z.w = 0u;
        p[i] = z;
    }
}

// ---------- k2: fused gi + serial GRU recurrence ----------
// 32 WGs. cluster = bid>>3 owns batch rows [cluster*16,+16); jg = bid&7 owns
// h-cols [jg*64,+64); wave owns 16 cols (all 3 gates).
__global__ __launch_bounds__(256, 1) void gru_rec(
    const int* __restrict__ tok, const float* __restrict__ emb,
    const ushortT* __restrict__ wih2, const ushortT* __restrict__ whh2,
    const float* __restrict__ bih, const float* __restrict__ bhh,
    ushortT* __restrict__ hbuf, float* __restrict__ st,
    unsigned* __restrict__ ctr)
{
    __shared__ ushortT xl[2][2][16][264];   // x dbuf: [buf][hi/lo][16 b][256k pad 264]

    const int bid = blockIdx.x;
    const int cluster = bid >> 3;
    const int jg = bid & 7;
    const int tid = threadIdx.x;
    const int wave = tid >> 6;
    const int lane = tid & 63;
    const int ln = lane & 15, quad = lane >> 4;
    const int m0 = cluster * 16;
    const int j_lane = jg * 64 + wave * 16 + ln;

    // Preload W_hh hi fragments (static): 48 frags = 192 VGPRs.
    f16x8 Bh[3][16];
#pragma unroll
    for (int g = 0; g < 3; ++g) {
        const ushortT* wrow = whh2 + (size_t)(g * 512 + j_lane) * 512;
#pragma unroll
        for (int ks = 0; ks < 16; ++ks)
            Bh[g][ks] = *reinterpret_cast<const f16x8*>(wrow + ks * 32 + quad * 8);
    }
    const float bi_r = bih[j_lane],        bh_r = bhh[j_lane];
    const float bi_z = bih[512 + j_lane],  bh_z = bhh[512 + j_lane];
    const float bi_n = bih[1024 + j_lane], bh_n = bhh[1024 + j_lane];

    // Prologue: stage x_0 (split f16 hi/lo) into LDS buf 0.
    {
        const int r = tid >> 4, c0 = (tid & 15) * 16;
        const int token = tok[(m0 + r) * 512];
        const float* xr = emb + (size_t)token * 256 + c0;
#pragma unroll
        for (int i = 0; i < 16; ++i) {
            ushortT hi, lo; splitf(xr[i], hi, lo);
            xl[0][0][r][c0 + i] = hi; xl[0][1][r][c0 + i] = lo;
        }
    }
    __syncthreads();

    float hprev[4] = {0.f, 0.f, 0.f, 0.f};
    unsigned* myctr = ctr + cluster * 16;

    for (int t = 0; t < 512; ++t) {
        const int rb = t & 1;
        const int wb = rb ^ 1;

        // (a) prefetch x_{t+1} into other LDS buffer
        {
            const int r = tid >> 4, c0 = (tid & 15) * 16;
            const int tp = (t + 1) & 511;
            const int token = tok[(m0 + r) * 512 + tp];
            const float* xr = emb + (size_t)token * 256 + c0;
#pragma unroll
            for (int i = 0; i < 16; ++i) {
                ushortT hi, lo; splitf(xr[i], hi, lo);
                xl[wb][0][r][c0 + i] = hi; xl[wb][1][r][c0 + i] = lo;
            }
        }

        // (b) gi = x_t @ W_ih^T  (f16-split, overlaps barrier wait)
        f32x4 gm[3], gs[3];
#pragma unroll
        for (int g = 0; g < 3; ++g) { gm[g] = (f32x4){0.f,0.f,0.f,0.f}; gs[g] = (f32x4){0.f,0.f,0.f,0.f}; }
#pragma unroll
        for (int ks = 0; ks < 8; ++ks) {
            const int k = ks * 32 + quad * 8;
            f16x8 Axh = *reinterpret_cast<const f16x8*>(&xl[rb][0][ln][k]);
            f16x8 Axl = *reinterpret_cast<const f16x8*>(&xl[rb][1][ln][k]);
#pragma unroll
            for (int g = 0; g < 3; ++g) {
                const ushortT* wr = wih2 + (size_t)(g * 512 + j_lane) * 256 + k;
                f16x8 Wh = *reinterpret_cast<const f16x8*>(wr);
                f16x8 Wl = *reinterpret_cast<const f16x8*>(wr + 393216);
                gm[g] = MFMAH(Axh, Wh, gm[g]);
                gs[g] = MFMAH(Axh, Wl, gs[g]);
                gs[g] = MFMAH(Axl, Wh, gs[g]);
            }
        }

        // (c) cluster barrier: wait for all 8 WGs' step t-1 arrivals
        if (tid == 0) {
            const unsigned target = 8u * (unsigned)t;
            while (__hip_atomic_load(myctr, __ATOMIC_ACQUIRE, __HIP_MEMORY_SCOPE_AGENT) < target)
                __builtin_amdgcn_s_sleep(1);
        }
        __syncthreads();
        __threadfence();   // acquire: invalidate caches before reading peers' h

        // (d) gh = h_{t-1} @ W_hh^T  (h as f16 hi/lo pair)
        f32x4 hm[3], hs[3];
#pragma unroll
        for (int g = 0; g < 3; ++g) { hm[g] = (f32x4){0.f,0.f,0.f,0.f}; hs[g] = (f32x4){0.f,0.f,0.f,0.f}; }
        const ushortT* arow = hbuf + rb * HB_BUF + (m0 + ln) * 512;
#pragma unroll
        for (int ks = 0; ks < 16; ++ks) {
            const int k = ks * 32 + quad * 8;
            f16x8 Ah = *reinterpret_cast<const f16x8*>(arow + k);
            f16x8 Al = *reinterpret_cast<const f16x8*>(arow + HB_TRI + k);
#pragma unroll
            for (int g = 0; g < 3; ++g) {
                f16x8 Wl = *reinterpret_cast<const f16x8*>(
                    whh2 + 786432 + (size_t)(g * 512 + j_lane) * 512 + k);
                hm[g] = MFMAH(Ah, Bh[g][ks], hm[g]);
                hs[g] = MFMAH(Ah, Wl, hs[g]);
                hs[g] = MFMAH(Al, Bh[g][ks], hs[g]);
            }
        }

        // (e) gates (f32) + h_new; store f16 pair + f32 state
        ushortT* hw = hbuf + wb * HB_BUF;
#pragma unroll
        for (int r4 = 0; r4 < 4; ++r4) {
            const float gi_r = gm[0][r4] + gs[0][r4] * KSC + bi_r;
            const float gi_z = gm[1][r4] + gs[1][r4] * KSC + bi_z;
            const float gi_n = gm[2][r4] + gs[2][r4] * KSC + bi_n;
            const float gh_r = hm[0][r4] + hs[0][r4] * KSC + bh_r;
            const float gh_z = hm[1][r4] + hs[1][r4] * KSC + bh_z;
            const float gh_n = hm[2][r4] + hs[2][r4] * KSC + bh_n;
            const float rr = 1.f / (1.f + expf(-(gi_r + gh_r)));
            const float zz = 1.f / (1.f + expf(-(gi_z + gh_z)));
            const float nn = tanhf(gi_n + rr * gh_n);
            const float hn = (1.f - zz) * nn + zz * hprev[r4];
            hprev[r4] = hn;
            ushortT hi, lo; splitf(hn, hi, lo);
            const int b = m0 + quad * 4 + r4;
            const int hidx = b * 512 + j_lane;
            hw[hidx] = hi;
            hw[HB_TRI + hidx] = lo;
            st[((size_t)b * 512 + t) * 512 + j_lane] = hn;
        }

        __syncthreads();
        __threadfence();   // release: flush h stores before arrival
        if (tid == 0)
            __hip_atomic_fetch_add(myctr, 1u, __ATOMIC_ACQ_REL, __HIP_MEMORY_SCOPE_AGENT);
    }
}

// ---------- k3: tag logits + argmax + PAD mask ----------
// M = 32768 (m = b*512+t), K = 512, N = 64. A: f32 states split on the fly.
__global__ __launch_bounds__(256) void tag_argmax(
    const float* __restrict__ st, const ushortT* __restrict__ wtag2,
    const float* __restrict__ btag, const int* __restrict__ tok,
    float* __restrict__ out)
{
    const int wave = threadIdx.x >> 6;
    const int lane = threadIdx.x & 63;
    const int ln = lane & 15, quad = lane >> 4;
    const int mt = blockIdx.x * 4 + wave;   // 0..2047

    const float* arow = st + (size_t)(mt * 16 + ln) * 512;
    f32x4 am[4], as_[4];
#pragma unroll
    for (int ti = 0; ti < 4; ++ti) { am[ti] = (f32x4){0.f,0.f,0.f,0.f}; as_[ti] = (f32x4){0.f,0.f,0.f,0.f}; }

#pragma unroll
    for (int ks = 0; ks < 16; ++ks) {
        const int k = ks * 32 + quad * 8;
        f16x8 Ah, Al;
#pragma unroll
        for (int e = 0; e < 8; ++e) {
            const float x = arow[k + e];
            _Float16 h = (_Float16)x;
            Ah[e] = h;
            Al[e] = (_Float16)((x - (float)h) * 4096.0f);
        }
#pragma unroll
        for (int ti = 0; ti < 4; ++ti) {
            const ushortT* wr = wtag2 + (size_t)(ti * 16 + ln) * 512 + k;
            f16x8 Wh = *reinterpret_cast<const f16x8*>(wr);
            f16x8 Wl = *reinterpret_cast<const f16x8*>(wr + 32768);
            am[ti]  = MFMAH(Ah, Wh, am[ti]);
            as_[ti] = MFMAH(Ah, Wl, as_[ti]);
            as_[ti] = MFMAH(Al, Wh, as_[ti]);
        }
    }

    float vals[4][4];
#pragma unroll
    for (int ti = 0; ti < 4; ++ti) {
        const float bb = btag[ti * 16 + ln];
#pragma unroll
        for (int r = 0; r < 4; ++r) vals[ti][r] = am[ti][r] + as_[ti][r] * KSC + bb;
    }
    // logits f32: row = mt*16 + quad*4 + r, col = ti*16 + ln
#pragma unroll
    for (int ti = 0; ti < 4; ++ti)
#pragma unroll
        for (int r = 0; r < 4; ++r) {
            const int row = mt * 16 + quad * 4 + r;
            out[(size_t)row * 64 + ti * 16 + ln] = vals[ti][r];
        }
    // argmax per row, first-index tie-break (np.argmax)
#pragma unroll
    for (int r = 0; r < 4; ++r) {
        float best = vals[0][r];
        int bc = ln;
#pragma unroll
        for (int ti = 1; ti < 4; ++ti) {
            const float v = vals[ti][r];
            const int c = ti * 16 + ln;
            if (v > best) { best = v; bc = c; }
        }
        for (int off = 1; off < 16; off <<= 1) {
            const float ov = __shfl_xor(best, off);
            const int oc = __shfl_xor(bc, off);
            if (ov > best || (ov == best && oc < bc)) { best = ov; bc = oc; }
        }
        if (ln == 0) {
            const int row = mt * 16 + quad * 4 + r;   // = b*512+t = token idx
            const int token = tok[row];
            const int pred = (token != 0) ? bc : 0;
            out[2097152 + (size_t)row] = (float)pred;
        }
    }
}

extern "C" void kernel_launch(void* const* d_in, const int* in_sizes, int n_in,
                              void* d_out, int out_size, void* d_ws, size_t ws_size,
                              hipStream_t stream) {
    const int*   tokens = (const int*)d_in[0];
    const float* emb    = (const float*)d_in[1];
    const float* Wih    = (const float*)d_in[2];
    const float* Whh    = (const float*)d_in[3];
    const float* bih    = (const float*)d_in[4];
    const float* bhh    = (const float*)d_in[5];
    const float* Wtag   = (const float*)d_in[6];
    const float* btag   = (const float*)d_in[7];

    char* ws = (char*)d_ws;
    unsigned* ctr   = (unsigned*)ws;                 // 256 B
    ushortT*  hbuf  = (ushortT*)(ws + 256);          // 262,144 B
    ushortT*  whh2  = (ushortT*)(ws + 262400);       // 3,145,728 B
    ushortT*  wih2  = (ushortT*)(ws + 3408128);      // 1,572,864 B
    ushortT*  wtag2 = (ushortT*)(ws + 4980992);      // 131,072 B
    float*    stf   = (float*)(ws + 5112064);        // 67,108,864 B (total 72.2 MB)
    float*    out   = (float*)d_out;

    split_weights<<<4736, 256, 0, stream>>>(Whh, Wih, Wtag, whh2, wih2, wtag2);
    init_ws<<<65, 256, 0, stream>>>((uint4*)ws);
    gru_rec<<<32, 256, 0, stream>>>(tokens, emb, wih2, whh2, bih, bhh, hbuf, stf, ctr);
    tag_argmax<<<512, 256, 0, stream>>>(stf, wtag2, btag, tokens, out);
}